// Round 1
// baseline (490.800 us; speedup 1.0000x reference)
//
#include <hip/hip_runtime.h>

// L=1024, B=4, IN=D=256, H=8, HD=32, IN2D=16
// ws layout (floats): q[1<<20] | k[1<<20] | v[1<<20] | o_part[JS<<20] | lsum_part[JS<<15]

__global__ __launch_bounds__(256) void qkv_proj(
    const float* __restrict__ s, const float* __restrict__ Wq,
    const float* __restrict__ Wk, const float* __restrict__ Wv,
    float* __restrict__ q_ws, float* __restrict__ k_ws, float* __restrict__ v_ws)
{
  __shared__ float s_lds[16][256];
  const int t = threadIdx.x;
  const int r0 = blockIdx.x << 4;
  for (int rr = 0; rr < 16; ++rr)
    s_lds[rr][t] = s[(size_t)(r0 + rr) * 256 + t];
  __syncthreads();
  float aq[16], ak[16], av[16];
#pragma unroll
  for (int rr = 0; rr < 16; ++rr) { aq[rr] = 0.f; ak[rr] = 0.f; av[rr] = 0.f; }
  for (int k = 0; k < 256; ++k) {
    const float wq = Wq[k * 256 + t];
    const float wk = Wk[k * 256 + t];
    const float wv = Wv[k * 256 + t];
#pragma unroll
    for (int rr = 0; rr < 16; ++rr) {
      const float sv = s_lds[rr][k];
      aq[rr] = fmaf(sv, wq, aq[rr]);
      ak[rr] = fmaf(sv, wk, ak[rr]);
      av[rr] = fmaf(sv, wv, av[rr]);
    }
  }
#pragma unroll
  for (int rr = 0; rr < 16; ++rr) {
    const int r = r0 + rr;
    const int l = r >> 2, b = r & 3;
    const size_t o = (((size_t)(b << 10) + l) << 8) + t;  // [b][l][d]
    q_ws[o] = aq[rr] * 0.0625f;  // 1/sqrt(256)
    k_ws[o] = ak[rr];
    v_ws[o] = av[rr];
  }
}

__global__ __launch_bounds__(256) void attn_fused(
    const float* __restrict__ q_ws, const float* __restrict__ k_ws,
    const float* __restrict__ v_ws, const float* __restrict__ p,
    const float* __restrict__ W2d, const float* __restrict__ b2d,
    float* __restrict__ o_part, float* __restrict__ lsum_part, int JS)
{
  __shared__ __align__(16) float q_lds[16][8][36];   // padded: conflict-free, 16B-aligned rows
  __shared__ __align__(16) float e2[8][16][32];      // e2[h][ii][jj]
  __shared__ __align__(16) float w2d_s[128];
  __shared__ float b2d_s[8];
  const int t = threadIdx.x;
  const int b = blockIdx.y;
  const int i0 = blockIdx.x << 4;
  const int js = blockIdx.z;
  const int h = t >> 5;
  const int dl = t & 31;
  if (t < 128) w2d_s[t] = W2d[t];
  if (t < 8) b2d_s[t] = b2d[t];
  for (int ii = 0; ii < 16; ++ii)
    q_lds[ii][h][dl] = q_ws[(((size_t)(b << 10) + i0 + ii) << 8) + t];

  float o_acc[16], ls_b[16];
#pragma unroll
  for (int ii = 0; ii < 16; ++ii) { o_acc[ii] = 0.f; ls_b[ii] = 0.f; }

  const int chunk = 1024 / JS;
  const int jbeg = js * chunk, jend = jbeg + chunk;
  for (int j0 = jbeg; j0 < jend; j0 += 32) {
    __syncthreads();  // protect e2 from previous tile's phase C
    // ---- Phase A: pairwise bias -> e2 ----
    {
      const int jj = dl;
#pragma unroll
      for (int half = 0; half < 2; ++half) {
        const int ii = h + (half << 3);
        const float4* p4 = (const float4*)(p + (((size_t)b << 24))
                                             + (((size_t)(i0 + ii)) << 14)
                                             + (((size_t)(j0 + jj)) << 4));
        const float4 pv0 = p4[0], pv1 = p4[1], pv2 = p4[2], pv3 = p4[3];
        const float4* w4 = (const float4*)w2d_s;
#pragma unroll
        for (int h2 = 0; h2 < 8; ++h2) {
          const float4 w0 = w4[h2 * 4 + 0], w1 = w4[h2 * 4 + 1];
          const float4 w2 = w4[h2 * 4 + 2], w3 = w4[h2 * 4 + 3];
          float a = b2d_s[h2];
          a += pv0.x * w0.x + pv0.y * w0.y + pv0.z * w0.z + pv0.w * w0.w;
          a += pv1.x * w1.x + pv1.y * w1.y + pv1.z * w1.z + pv1.w * w1.w;
          a += pv2.x * w2.x + pv2.y * w2.y + pv2.z * w2.z + pv2.w * w2.w;
          a += pv3.x * w3.x + pv3.y * w3.y + pv3.z * w3.z + pv3.w * w3.w;
          e2[h2][ii][jj] = a;
        }
      }
    }
    __syncthreads();
    // ---- Phase B: scores + exp ----
    {
      const int jj = dl;
      float kr[32];
      const float4* k4 = (const float4*)(k_ws + (((size_t)(b << 10) + j0 + jj) << 8) + (h << 5));
#pragma unroll
      for (int d4 = 0; d4 < 8; ++d4) {
        const float4 kk = k4[d4];
        kr[4 * d4 + 0] = kk.x; kr[4 * d4 + 1] = kk.y;
        kr[4 * d4 + 2] = kk.z; kr[4 * d4 + 3] = kk.w;
      }
      for (int ii = 0; ii < 16; ++ii) {
        float a = e2[h][ii][jj];
        const float4* q4 = (const float4*)(&q_lds[ii][h][0]);
#pragma unroll
        for (int d4 = 0; d4 < 8; ++d4) {
          const float4 qq = q4[d4];
          a += qq.x * kr[4 * d4 + 0] + qq.y * kr[4 * d4 + 1]
             + qq.z * kr[4 * d4 + 2] + qq.w * kr[4 * d4 + 3];
        }
        const float ex = __expf(a);
        e2[h][ii][jj] = ex;
        ls_b[ii] += ex;   // per-thread partial row-sum (this jj only)
      }
    }
    __syncthreads();
    // ---- Phase C: PV accumulation ----
    {
#pragma unroll
      for (int jj4 = 0; jj4 < 8; ++jj4) {
        const size_t vb = (((size_t)(b << 10) + j0 + (jj4 << 2)) << 8) + t;
        const float v0 = v_ws[vb];
        const float v1 = v_ws[vb + 256];
        const float v2 = v_ws[vb + 512];
        const float v3 = v_ws[vb + 768];
#pragma unroll
        for (int ii = 0; ii < 16; ++ii) {
          const float4 ev = *(const float4*)(&e2[h][ii][jj4 << 2]);
          o_acc[ii] = fmaf(ev.x, v0, o_acc[ii]);
          o_acc[ii] = fmaf(ev.y, v1, o_acc[ii]);
          o_acc[ii] = fmaf(ev.z, v2, o_acc[ii]);
          o_acc[ii] = fmaf(ev.w, v3, o_acc[ii]);
        }
      }
    }
  }
  // finalize lsum: reduce ls_b over the 32 lanes of this h-group
#pragma unroll
  for (int ii = 0; ii < 16; ++ii) {
    float v = ls_b[ii];
    v += __shfl_xor(v, 1, 32);
    v += __shfl_xor(v, 2, 32);
    v += __shfl_xor(v, 4, 32);
    v += __shfl_xor(v, 8, 32);
    v += __shfl_xor(v, 16, 32);
    ls_b[ii] = v;
  }
  const size_t ob = ((size_t)js << 20) + (((size_t)(b << 10) + i0) << 8) + t;
#pragma unroll
  for (int ii = 0; ii < 16; ++ii)
    o_part[ob + ((size_t)ii << 8)] = o_acc[ii];
  if (dl == 0) {
    const size_t lb = ((size_t)js << 15) + (((size_t)(b << 10) + i0) << 3) + h;
#pragma unroll
    for (int ii = 0; ii < 16; ++ii)
      lsum_part[lb + (ii << 3)] = ls_b[ii];
  }
}

__global__ __launch_bounds__(256) void out_proj(
    const float* __restrict__ o_part, const float* __restrict__ lsum_part,
    const float* __restrict__ Wo, const float* __restrict__ bo,
    float* __restrict__ out, int JS)
{
  __shared__ float o_lds[16][256];
  const int t = threadIdx.x;
  const int r0 = blockIdx.x << 4;
  const int h = t >> 5;
  for (int rr = 0; rr < 16; ++rr) {
    const int r = r0 + rr;
    const int l = r >> 2, bb = r & 3;
    const size_t base = (((size_t)(bb << 10) + l) << 8) + t;
    float acc = 0.f;
    for (int js = 0; js < JS; ++js)
      acc += o_part[((size_t)js << 20) + base];
    float lsv = 0.f;
    const size_t lbase = (((size_t)(bb << 10) + l) << 3) + h;
    for (int js = 0; js < JS; ++js)
      lsv += lsum_part[((size_t)js << 15) + lbase];
    o_lds[rr][t] = acc / lsv;
  }
  __syncthreads();
  float accs[16];
#pragma unroll
  for (int rr = 0; rr < 16; ++rr) accs[rr] = 0.f;
  for (int k = 0; k < 256; ++k) {
    const float wo = Wo[k * 256 + t];
#pragma unroll
    for (int rr = 0; rr < 16; ++rr)
      accs[rr] = fmaf(o_lds[rr][k], wo, accs[rr]);
  }
  const float bov = bo[t];
#pragma unroll
  for (int rr = 0; rr < 16; ++rr)
    out[(size_t)(r0 + rr) * 256 + t] = accs[rr] + bov;
}

extern "C" void kernel_launch(void* const* d_in, const int* in_sizes, int n_in,
                              void* d_out, int out_size, void* d_ws, size_t ws_size,
                              hipStream_t stream)
{
  const float* s   = (const float*)d_in[0];
  const float* p   = (const float*)d_in[3];
  const float* Wq  = (const float*)d_in[4];
  const float* Wk  = (const float*)d_in[5];
  const float* Wv  = (const float*)d_in[6];
  const float* Wo  = (const float*)d_in[7];
  const float* bo  = (const float*)d_in[8];
  const float* W2d = (const float*)d_in[9];
  const float* b2d = (const float*)d_in[10];
  float* out = (float*)d_out;

  float* q_ws = (float*)d_ws;
  float* k_ws = q_ws + (1 << 20);
  float* v_ws = k_ws + (1 << 20);
  float* o_part = v_ws + (1 << 20);

  auto need = [](int js) -> size_t {
    return (size_t)12 * (1 << 20) * 1u  // 12M floats? no: bytes below
        ;
  };
  (void)need;
  // bytes: qkv = 3*(1<<20)*4 = 12MB; per js: o_part 4MB + lsum 128KB
  int JS = 4;
  {
    const size_t base_b = (size_t)3 * (1 << 20) * 4;
    const size_t per_js = (size_t)(1 << 20) * 4 + (size_t)(1 << 15) * 4;
    if (base_b + 4 * per_js > ws_size) JS = (base_b + 2 * per_js <= ws_size) ? 2 : 1;
  }
  float* lsum_part = o_part + ((size_t)JS << 20);

  qkv_proj<<<dim3(256), dim3(256), 0, stream>>>(s, Wq, Wk, Wv, q_ws, k_ws, v_ws);
  attn_fused<<<dim3(64, 4, JS), dim3(256), 0, stream>>>(q_ws, k_ws, v_ws, p, W2d, b2d,
                                                        o_part, lsum_part, JS);
  out_proj<<<dim3(256), dim3(256), 0, stream>>>(o_part, lsum_part, Wo, bo, out, JS);
}

// Round 2
// 308.096 us; speedup vs baseline: 1.5930x; 1.5930x over previous
//
#include <hip/hip_runtime.h>

// L=1024, B=4, IN=D=256, H=8, HD=32, IN2D=16
// ws floats: q[1M] | k[1M] | v[1M] | o_part[JS*1M] | lsum_part[JS*32768]

typedef __attribute__((ext_vector_type(8))) short short8;
typedef __attribute__((ext_vector_type(4))) float f32x4;

__device__ inline unsigned short f2bf(float f) {
  unsigned int u = __float_as_uint(f);
  return (unsigned short)((u + 0x7FFFu + ((u >> 16) & 1u)) >> 16);
}

__device__ inline short8 pack_bf8(float4 a, float4 b) {
  short8 r;
  r[0] = (short)f2bf(a.x); r[1] = (short)f2bf(a.y);
  r[2] = (short)f2bf(a.z); r[3] = (short)f2bf(a.w);
  r[4] = (short)f2bf(b.x); r[5] = (short)f2bf(b.y);
  r[6] = (short)f2bf(b.z); r[7] = (short)f2bf(b.w);
  return r;
}

__global__ __launch_bounds__(256) void qkv_proj(
    const float* __restrict__ s, const float* __restrict__ Wq,
    const float* __restrict__ Wk, const float* __restrict__ Wv,
    float* __restrict__ q_ws, float* __restrict__ k_ws, float* __restrict__ v_ws)
{
  __shared__ float s_lds[16][256];
  const int t = threadIdx.x;
  const int r0 = blockIdx.x << 4;
  for (int rr = 0; rr < 16; ++rr)
    s_lds[rr][t] = s[(size_t)(r0 + rr) * 256 + t];
  __syncthreads();
  float aq[16], ak[16], av[16];
#pragma unroll
  for (int rr = 0; rr < 16; ++rr) { aq[rr] = 0.f; ak[rr] = 0.f; av[rr] = 0.f; }
  for (int k = 0; k < 256; ++k) {
    const float wq = Wq[k * 256 + t];
    const float wk = Wk[k * 256 + t];
    const float wv = Wv[k * 256 + t];
#pragma unroll
    for (int rr = 0; rr < 16; ++rr) {
      const float sv = s_lds[rr][k];
      aq[rr] = fmaf(sv, wq, aq[rr]);
      ak[rr] = fmaf(sv, wk, ak[rr]);
      av[rr] = fmaf(sv, wv, av[rr]);
    }
  }
#pragma unroll
  for (int rr = 0; rr < 16; ++rr) {
    const int r = r0 + rr;
    const int l = r >> 2, b = r & 3;
    const size_t o = (((size_t)(b << 10) + l) << 8) + t;  // [b][l][d]
    q_ws[o] = aq[rr] * 0.0625f;  // 1/sqrt(256)
    k_ws[o] = ak[rr];
    v_ws[o] = av[rr];
  }
}

__global__ __launch_bounds__(256) void attn_mfma(
    const float* __restrict__ q_ws, const float* __restrict__ k_ws,
    const float* __restrict__ v_ws, const float* __restrict__ p,
    const float* __restrict__ W2d, const float* __restrict__ b2d,
    float* __restrict__ o_part, float* __restrict__ lsum_part, int JS)
{
  __shared__ __align__(16) float e2[8][16][36];            // padded: <=2-way conflicts
  __shared__ __align__(16) unsigned short p_lds[8][16][40]; // bf16 P, 80B rows (16B-aligned)
  __shared__ __align__(16) float w2d_s[128];
  __shared__ float b2d_s[8];

  const int t = threadIdx.x;
  const int b = blockIdx.y;
  const int i0 = blockIdx.x << 4;
  const int js = blockIdx.z;
  const int w = t >> 6;      // wave 0..3 -> heads 2w, 2w+1
  const int l = t & 63;
  const int lrow = l & 15;   // frag row / col index
  const int lgrp = l >> 4;   // frag k-group / row-group

  if (t < 128) w2d_s[t] = W2d[t];
  if (t < 8) b2d_s[t] = b2d[t];

  // hoist Q A-fragments (per block, per head-pair): A[row=i][k=d_in_head]
  short8 qa[2];
#pragma unroll
  for (int h2 = 0; h2 < 2; ++h2) {
    const int h = (w << 1) + h2;
    const float* qp = q_ws + (((size_t)(b << 10) + i0 + lrow) << 8) + (h << 5) + (lgrp << 3);
    qa[h2] = pack_bf8(*(const float4*)qp, *(const float4*)(qp + 4));
  }

  f32x4 o_acc[2][2];
  float ls[2][4];
#pragma unroll
  for (int h2 = 0; h2 < 2; ++h2) {
#pragma unroll
    for (int nh = 0; nh < 2; ++nh) o_acc[h2][nh] = (f32x4){0.f, 0.f, 0.f, 0.f};
#pragma unroll
    for (int r = 0; r < 4; ++r) ls[h2][r] = 0.f;
  }

  __syncthreads();  // w2d_s ready

  const int chunk = 1024 / JS;
  const int jbeg = js * chunk, jend = jbeg + chunk;
  for (int j0 = jbeg; j0 < jend; j0 += 32) {
    // ---- Phase A: pairwise bias MLP -> e2[h][ii][jj] (fp32 VALU, cooperative) ----
    {
      const int ha = t >> 5;
      const int jj = t & 31;
#pragma unroll
      for (int half = 0; half < 2; ++half) {
        const int ii = ha + (half << 3);
        const float4* p4 = (const float4*)(p + ((size_t)b << 24)
                                             + (((size_t)(i0 + ii)) << 14)
                                             + (((size_t)(j0 + jj)) << 4));
        const float4 pv0 = p4[0], pv1 = p4[1], pv2 = p4[2], pv3 = p4[3];
        const float4* w4 = (const float4*)w2d_s;
#pragma unroll
        for (int hh = 0; hh < 8; ++hh) {
          const float4 w0 = w4[hh * 4 + 0], w1 = w4[hh * 4 + 1];
          const float4 w2 = w4[hh * 4 + 2], w3 = w4[hh * 4 + 3];
          float a = b2d_s[hh];
          a += pv0.x * w0.x + pv0.y * w0.y + pv0.z * w0.z + pv0.w * w0.w;
          a += pv1.x * w1.x + pv1.y * w1.y + pv1.z * w1.z + pv1.w * w1.w;
          a += pv2.x * w2.x + pv2.y * w2.y + pv2.z * w2.z + pv2.w * w2.w;
          a += pv3.x * w3.x + pv3.y * w3.y + pv3.z * w3.z + pv3.w * w3.w;
          e2[hh][ii][jj] = a;
        }
      }
    }
    __syncthreads();

    // ---- Scores: D = Q*K^T + bias (MFMA), exp in-register, P -> bf16 LDS ----
#pragma unroll
    for (int h2 = 0; h2 < 2; ++h2) {
      const int h = (w << 1) + h2;
#pragma unroll
      for (int jh = 0; jh < 2; ++jh) {
        const int j = j0 + (jh << 4) + lrow;       // B col = j
        const float* kp = k_ws + (((size_t)(b << 10) + j) << 8) + (h << 5) + (lgrp << 3);
        const short8 kb = pack_bf8(*(const float4*)kp, *(const float4*)(kp + 4));
        f32x4 c;
#pragma unroll
        for (int r = 0; r < 4; ++r)
          c[r] = e2[h][(lgrp << 2) + r][(jh << 4) + lrow];
        f32x4 d = __builtin_amdgcn_mfma_f32_16x16x32_bf16(qa[h2], kb, c, 0, 0, 0);
#pragma unroll
        for (int r = 0; r < 4; ++r) {
          const float ex = __expf(d[r]);
          ls[h2][r] += ex;
          p_lds[h][(lgrp << 2) + r][(jh << 4) + lrow] = f2bf(ex);
        }
      }
    }

    // ---- PV: o += P * V (MFMA); P from LDS (A-frag), V direct from global (B-frag) ----
#pragma unroll
    for (int h2 = 0; h2 < 2; ++h2) {
      const int h = (w << 1) + h2;
      const short8 pa = *(const short8*)&p_lds[h][lrow][lgrp << 3];
#pragma unroll
      for (int nh = 0; nh < 2; ++nh) {
        const int d = (h << 5) + (nh << 4) + lrow;  // B col = d
        short8 vb;
#pragma unroll
        for (int e = 0; e < 8; ++e) {
          const float vf = v_ws[(((size_t)(b << 10) + j0 + (lgrp << 3) + e) << 8) + d];
          vb[e] = (short)f2bf(vf);
        }
        o_acc[h2][nh] = __builtin_amdgcn_mfma_f32_16x16x32_bf16(pa, vb, o_acc[h2][nh], 0, 0, 0);
      }
    }
    __syncthreads();  // protect e2 for next tile's Phase A
  }

  // ---- epilogue: reduce row-sums across the 16 col-lanes, store partials ----
#pragma unroll
  for (int h2 = 0; h2 < 2; ++h2) {
#pragma unroll
    for (int r = 0; r < 4; ++r) {
      float v = ls[h2][r];
      v += __shfl_xor(v, 1, 16);
      v += __shfl_xor(v, 2, 16);
      v += __shfl_xor(v, 4, 16);
      v += __shfl_xor(v, 8, 16);
      ls[h2][r] = v;
    }
  }
  const size_t obase = ((size_t)js << 20) + (((size_t)(b << 10) + i0) << 8);
#pragma unroll
  for (int h2 = 0; h2 < 2; ++h2) {
    const int h = (w << 1) + h2;
#pragma unroll
    for (int nh = 0; nh < 2; ++nh) {
      const int d = (h << 5) + (nh << 4) + lrow;
#pragma unroll
      for (int r = 0; r < 4; ++r)
        o_part[obase + ((size_t)((lgrp << 2) + r) << 8) + d] = o_acc[h2][nh][r];
    }
  }
  if (lrow == 0) {
#pragma unroll
    for (int h2 = 0; h2 < 2; ++h2) {
      const int h = (w << 1) + h2;
      float* lp = lsum_part + (((size_t)((js << 5) + (b << 3) + h)) << 10) + i0;
#pragma unroll
      for (int r = 0; r < 4; ++r)
        lp[(lgrp << 2) + r] = ls[h2][r];
    }
  }
}

__global__ __launch_bounds__(256) void out_proj(
    const float* __restrict__ o_part, const float* __restrict__ lsum_part,
    const float* __restrict__ Wo, const float* __restrict__ bo,
    float* __restrict__ out, int JS)
{
  __shared__ float o_lds[16][256];
  const int t = threadIdx.x;
  const int r0 = blockIdx.x << 4;
  const int h = t >> 5;
  for (int rr = 0; rr < 16; ++rr) {
    const int r = r0 + rr;
    const int l = r >> 2, bb = r & 3;
    const size_t base = (((size_t)(bb << 10) + l) << 8) + t;
    float acc = 0.f;
    for (int js = 0; js < JS; ++js)
      acc += o_part[((size_t)js << 20) + base];
    float lsv = 0.f;
    for (int js = 0; js < JS; ++js)
      lsv += lsum_part[(((size_t)((js << 5) + (bb << 3) + h)) << 10) + l];
    o_lds[rr][t] = acc / lsv;
  }
  __syncthreads();
  float accs[16];
#pragma unroll
  for (int rr = 0; rr < 16; ++rr) accs[rr] = 0.f;
  for (int k = 0; k < 256; ++k) {
    const float wo = Wo[k * 256 + t];
#pragma unroll
    for (int rr = 0; rr < 16; ++rr)
      accs[rr] = fmaf(o_lds[rr][k], wo, accs[rr]);
  }
  const float bov = bo[t];
#pragma unroll
  for (int rr = 0; rr < 16; ++rr)
    out[(size_t)(r0 + rr) * 256 + t] = accs[rr] + bov;
}

extern "C" void kernel_launch(void* const* d_in, const int* in_sizes, int n_in,
                              void* d_out, int out_size, void* d_ws, size_t ws_size,
                              hipStream_t stream)
{
  const float* s   = (const float*)d_in[0];
  const float* p   = (const float*)d_in[3];
  const float* Wq  = (const float*)d_in[4];
  const float* Wk  = (const float*)d_in[5];
  const float* Wv  = (const float*)d_in[6];
  const float* Wo  = (const float*)d_in[7];
  const float* bo  = (const float*)d_in[8];
  const float* W2d = (const float*)d_in[9];
  const float* b2d = (const float*)d_in[10];
  float* out = (float*)d_out;

  float* q_ws = (float*)d_ws;
  float* k_ws = q_ws + (1 << 20);
  float* v_ws = k_ws + (1 << 20);
  float* o_part = v_ws + (1 << 20);

  // bytes: qkv = 12MB; per js slice: o_part 4MB + lsum 128KB
  int JS = 8;
  {
    const size_t base_b = (size_t)3 * (1 << 20) * 4;
    const size_t per_js = (size_t)(1 << 20) * 4 + (size_t)(1 << 15) * 4;
    while (JS > 1 && base_b + (size_t)JS * per_js > ws_size) JS >>= 1;
  }
  float* lsum_part = o_part + ((size_t)JS << 20);

  qkv_proj<<<dim3(256), dim3(256), 0, stream>>>(s, Wq, Wk, Wv, q_ws, k_ws, v_ws);
  attn_mfma<<<dim3(64, 4, JS), dim3(256), 0, stream>>>(q_ws, k_ws, v_ws, p, W2d, b2d,
                                                       o_part, lsum_part, JS);
  out_proj<<<dim3(256), dim3(256), 0, stream>>>(o_part, lsum_part, Wo, bo, out, JS);
}

// Round 3
// 212.647 us; speedup vs baseline: 2.3081x; 1.4489x over previous
//
#include <hip/hip_runtime.h>

// L=1024, B=4, IN=D=256, H=8, HD=32, IN2D=16
// ws: q_bf[1M] k_bf[1M] v_t[1M] (ushort) | o_part[JS*1M] lsum_part[JS*32K] (float)

typedef __attribute__((ext_vector_type(8))) short short8;
typedef __attribute__((ext_vector_type(4))) float f32x4;
typedef unsigned short ushort_t;

__device__ inline unsigned short f2bf(float f) {
  unsigned int u = __float_as_uint(f);
  return (unsigned short)((u + 0x7FFFu + ((u >> 16) & 1u)) >> 16);
}

__global__ __launch_bounds__(256) void qkv_proj(
    const float* __restrict__ s, const float* __restrict__ Wq,
    const float* __restrict__ Wk, const float* __restrict__ Wv,
    ushort_t* __restrict__ q_bf, ushort_t* __restrict__ k_bf, ushort_t* __restrict__ v_t)
{
  __shared__ float s_lds[8][256];
  const int t = threadIdx.x;
  const int b = blockIdx.x >> 7;          // fixed batch per block
  const int l0 = (blockIdx.x & 127) << 3; // 8 consecutive l
  for (int rr = 0; rr < 8; ++rr)
    s_lds[rr][t] = s[((size_t)(((l0 + rr) << 2) + b) << 8) + t];
  __syncthreads();
  float aq[8], ak[8], av[8];
#pragma unroll
  for (int rr = 0; rr < 8; ++rr) { aq[rr] = 0.f; ak[rr] = 0.f; av[rr] = 0.f; }
  for (int k = 0; k < 256; ++k) {
    const float wq = Wq[k * 256 + t];
    const float wk = Wk[k * 256 + t];
    const float wv = Wv[k * 256 + t];
#pragma unroll
    for (int rr = 0; rr < 8; ++rr) {
      const float sv = s_lds[rr][k];
      aq[rr] = fmaf(sv, wq, aq[rr]);
      ak[rr] = fmaf(sv, wk, ak[rr]);
      av[rr] = fmaf(sv, wv, av[rr]);
    }
  }
  const int h = t >> 5, dl = t & 31;
#pragma unroll
  for (int rr = 0; rr < 8; ++rr) {
    const int l = l0 + rr;
    q_bf[(((size_t)(b << 10) + l) << 8) + t] = f2bf(aq[rr] * 0.0625f);
    k_bf[((((size_t)((b << 3) + h) << 10) + l) << 5) + dl] = f2bf(ak[rr]);
  }
  short8 vv;
#pragma unroll
  for (int rr = 0; rr < 8; ++rr) vv[rr] = (short)f2bf(av[rr]);
  *(short8*)&v_t[((((size_t)((b << 3) + h) << 5) + dl) << 10) + l0] = vv;
}

__global__ __launch_bounds__(256) void attn_mfma(
    const ushort_t* __restrict__ q_bf, const ushort_t* __restrict__ k_bf,
    const ushort_t* __restrict__ v_t, const float* __restrict__ p,
    const float* __restrict__ W2d, const float* __restrict__ b2d,
    float* __restrict__ o_part, float* __restrict__ lsum_part, int JS)
{
  __shared__ __align__(16) float e2[2][8][16][36];          // double-buffered bias
  __shared__ __align__(16) ushort_t p_lds[8][16][40];       // bf16 P (wave-local use)
  __shared__ __align__(16) float w2d_s[128];
  __shared__ float b2d_s[8];

  const int t = threadIdx.x;
  const int b = blockIdx.y;
  const int i0 = blockIdx.x << 4;
  const int js = blockIdx.z;
  const int w = t >> 6;      // wave -> heads 2w, 2w+1
  const int l = t & 63;
  const int lrow = l & 15;
  const int lgrp = l >> 4;
  const int ha = t >> 5;     // 0..7 (phase A i-row)
  const int jj = t & 31;     // phase A j-col

  if (t < 128) w2d_s[t] = W2d[t];
  if (t < 8) b2d_s[t] = b2d[t];

  short8 qa[2];
#pragma unroll
  for (int h2 = 0; h2 < 2; ++h2) {
    const int h = (w << 1) + h2;
    qa[h2] = *(const short8*)&q_bf[(((size_t)(b << 10) + i0 + lrow) << 8) + (h << 5) + (lgrp << 3)];
  }

  f32x4 o_acc[2][2];
  float ls[2][4];
#pragma unroll
  for (int h2 = 0; h2 < 2; ++h2) {
#pragma unroll
    for (int nh = 0; nh < 2; ++nh) o_acc[h2][nh] = (f32x4){0.f, 0.f, 0.f, 0.f};
#pragma unroll
    for (int r = 0; r < 4; ++r) ls[h2][r] = 0.f;
  }

  const float* pbase = p + ((size_t)b << 24) + ((size_t)jj << 4);
  float4 pv[2][4];
  auto PREF = [&](int j0) {
#pragma unroll
    for (int half = 0; half < 2; ++half) {
      const float4* p4 = (const float4*)(pbase + (((size_t)(i0 + ha + (half << 3))) << 14)
                                               + ((size_t)j0 << 4));
      pv[half][0] = p4[0]; pv[half][1] = p4[1];
      pv[half][2] = p4[2]; pv[half][3] = p4[3];
    }
  };

  const int chunk = 1024 / JS;
  const int jbeg = js * chunk, jend = jbeg + chunk;
  PREF(jbeg);
  __syncthreads();  // w2d_s ready

  int buf = 0;
  for (int j0 = jbeg; j0 < jend; j0 += 32, buf ^= 1) {
    // ---- Phase A: bias MLP from prefetched p regs -> e2[buf] ----
    {
      const float4* w4 = (const float4*)w2d_s;
#pragma unroll
      for (int half = 0; half < 2; ++half) {
        const int ii = ha + (half << 3);
        const float4 pv0 = pv[half][0], pv1 = pv[half][1];
        const float4 pv2 = pv[half][2], pv3 = pv[half][3];
#pragma unroll
        for (int hh = 0; hh < 8; ++hh) {
          const float4 w0 = w4[hh * 4 + 0], w1 = w4[hh * 4 + 1];
          const float4 w2 = w4[hh * 4 + 2], w3 = w4[hh * 4 + 3];
          float a = b2d_s[hh];
          a += pv0.x * w0.x + pv0.y * w0.y + pv0.z * w0.z + pv0.w * w0.w;
          a += pv1.x * w1.x + pv1.y * w1.y + pv1.z * w1.z + pv1.w * w1.w;
          a += pv2.x * w2.x + pv2.y * w2.y + pv2.z * w2.z + pv2.w * w2.w;
          a += pv3.x * w3.x + pv3.y * w3.y + pv3.z * w3.z + pv3.w * w3.w;
          e2[buf][hh][ii][jj] = a;
        }
      }
    }
    if (j0 + 32 < jend) PREF(j0 + 32);   // hide next tile's p latency under MFMA
    __syncthreads();

    // ---- Scores: D = Q*K^T + bias, exp in-register, P -> bf16 LDS ----
#pragma unroll
    for (int h2 = 0; h2 < 2; ++h2) {
      const int h = (w << 1) + h2;
#pragma unroll
      for (int jh = 0; jh < 2; ++jh) {
        const int j = j0 + (jh << 4) + lrow;
        const short8 kb = *(const short8*)&k_bf[((((size_t)((b << 3) + h) << 10) + j) << 5) + (lgrp << 3)];
        f32x4 c;
#pragma unroll
        for (int r = 0; r < 4; ++r)
          c[r] = e2[buf][h][(lgrp << 2) + r][(jh << 4) + lrow];
        f32x4 d = __builtin_amdgcn_mfma_f32_16x16x32_bf16(qa[h2], kb, c, 0, 0, 0);
#pragma unroll
        for (int r = 0; r < 4; ++r) {
          const float ex = __expf(d[r]);
          ls[h2][r] += ex;
          p_lds[h][(lgrp << 2) + r][(jh << 4) + lrow] = f2bf(ex);
        }
      }
    }

    // ---- PV: o += P * V; P from LDS (A-frag), V via transposed bf16 (B-frag) ----
#pragma unroll
    for (int h2 = 0; h2 < 2; ++h2) {
      const int h = (w << 1) + h2;
      const short8 pa = *(const short8*)&p_lds[h][lrow][lgrp << 3];
#pragma unroll
      for (int nh = 0; nh < 2; ++nh) {
        const short8 vb = *(const short8*)&v_t[((((size_t)((b << 3) + h) << 5) + (nh << 4) + lrow) << 10) + j0 + (lgrp << 3)];
        o_acc[h2][nh] = __builtin_amdgcn_mfma_f32_16x16x32_bf16(pa, vb, o_acc[h2][nh], 0, 0, 0);
      }
    }
  }

  // ---- epilogue ----
#pragma unroll
  for (int h2 = 0; h2 < 2; ++h2) {
#pragma unroll
    for (int r = 0; r < 4; ++r) {
      float v = ls[h2][r];
      v += __shfl_xor(v, 1, 16);
      v += __shfl_xor(v, 2, 16);
      v += __shfl_xor(v, 4, 16);
      v += __shfl_xor(v, 8, 16);
      ls[h2][r] = v;
    }
  }
  const size_t obase = ((size_t)js << 20) + (((size_t)(b << 10) + i0) << 8);
#pragma unroll
  for (int h2 = 0; h2 < 2; ++h2) {
    const int h = (w << 1) + h2;
#pragma unroll
    for (int nh = 0; nh < 2; ++nh) {
      const int d = (h << 5) + (nh << 4) + lrow;
#pragma unroll
      for (int r = 0; r < 4; ++r)
        o_part[obase + ((size_t)((lgrp << 2) + r) << 8) + d] = o_acc[h2][nh][r];
    }
  }
  if (lrow == 0) {
#pragma unroll
    for (int h2 = 0; h2 < 2; ++h2) {
      const int h = (w << 1) + h2;
      float* lp = lsum_part + (((size_t)((js << 5) + (b << 3) + h)) << 10) + i0;
#pragma unroll
      for (int r = 0; r < 4; ++r)
        lp[(lgrp << 2) + r] = ls[h2][r];
    }
  }
}

__global__ __launch_bounds__(256) void out_proj(
    const float* __restrict__ o_part, const float* __restrict__ lsum_part,
    const float* __restrict__ Wo, const float* __restrict__ bo,
    float* __restrict__ out, int JS)
{
  __shared__ float o_lds[8][256];
  const int t = threadIdx.x;
  const int r0 = blockIdx.x << 3;
  const int h = t >> 5;
  for (int rr = 0; rr < 8; ++rr) {
    const int r = r0 + rr;
    const int l = r >> 2, bb = r & 3;
    const size_t base = (((size_t)(bb << 10) + l) << 8) + t;
    float acc = 0.f;
    for (int js = 0; js < JS; ++js)
      acc += o_part[((size_t)js << 20) + base];
    float lsv = 0.f;
    for (int js = 0; js < JS; ++js)
      lsv += lsum_part[(((size_t)((js << 5) + (bb << 3) + h)) << 10) + l];
    o_lds[rr][t] = acc / lsv;
  }
  __syncthreads();
  float accs[8];
#pragma unroll
  for (int rr = 0; rr < 8; ++rr) accs[rr] = 0.f;
  for (int k = 0; k < 256; ++k) {
    const float wo = Wo[k * 256 + t];
#pragma unroll
    for (int rr = 0; rr < 8; ++rr)
      accs[rr] = fmaf(o_lds[rr][k], wo, accs[rr]);
  }
  const float bov = bo[t];
#pragma unroll
  for (int rr = 0; rr < 8; ++rr)
    out[(size_t)(r0 + rr) * 256 + t] = accs[rr] + bov;
}

extern "C" void kernel_launch(void* const* d_in, const int* in_sizes, int n_in,
                              void* d_out, int out_size, void* d_ws, size_t ws_size,
                              hipStream_t stream)
{
  const float* s   = (const float*)d_in[0];
  const float* p   = (const float*)d_in[3];
  const float* Wq  = (const float*)d_in[4];
  const float* Wk  = (const float*)d_in[5];
  const float* Wv  = (const float*)d_in[6];
  const float* Wo  = (const float*)d_in[7];
  const float* bo  = (const float*)d_in[8];
  const float* W2d = (const float*)d_in[9];
  const float* b2d = (const float*)d_in[10];
  float* out = (float*)d_out;

  ushort_t* q_bf = (ushort_t*)d_ws;
  ushort_t* k_bf = q_bf + (1 << 20);
  ushort_t* v_t  = k_bf + (1 << 20);
  float* o_part = (float*)(v_t + (1 << 20));

  // bytes: qkv bf16 = 6MB; per js slice: o_part 4MB + lsum 128KB
  int JS = 8;
  {
    const size_t base_b = (size_t)3 * (1 << 20) * 2;
    const size_t per_js = (size_t)(1 << 20) * 4 + (size_t)(1 << 15) * 4;
    while (JS > 1 && base_b + (size_t)JS * per_js > ws_size) JS >>= 1;
  }
  float* lsum_part = o_part + ((size_t)JS << 20);

  qkv_proj<<<dim3(512), dim3(256), 0, stream>>>(s, Wq, Wk, Wv, q_bf, k_bf, v_t);
  attn_mfma<<<dim3(64, 4, JS), dim3(256), 0, stream>>>(q_bf, k_bf, v_t, p, W2d, b2d,
                                                       o_part, lsum_part, JS);
  out_proj<<<dim3(512), dim3(256), 0, stream>>>(o_part, lsum_part, Wo, bo, out, JS);
}